// Round 7
// baseline (1682.130 us; speedup 1.0000x reference)
//
#include <hip/hip_runtime.h>

#define HID   64
#define ENC_T 20
#define DEC_T 30
#define ROWS  32   // batch rows per tile: two 16-row MFMA n-tiles per wave
#define TILES 2    // row-tiles processed sequentially per block (persistent)
#define HS    72   // sH row stride in bf16 elems: 144B = 16B-aligned

typedef __bf16 bf16x8 __attribute__((ext_vector_type(8)));
typedef float  f32x4  __attribute__((ext_vector_type(4)));
typedef float  f32x2  __attribute__((ext_vector_type(2)));
typedef unsigned short u16x4 __attribute__((ext_vector_type(4)));
typedef unsigned short ushort_t;
typedef unsigned int   uint_t;

#if __has_builtin(__builtin_amdgcn_exp2f)
#define EXP2F(x) __builtin_amdgcn_exp2f(x)
#else
#define EXP2F(x) exp2f(x)
#endif
#if __has_builtin(__builtin_amdgcn_rcpf)
#define RCPF(x) __builtin_amdgcn_rcpf(x)
#else
#define RCPF(x) (1.0f / (x))
#endif

#define L2E 1.4426950408889634f

__device__ __forceinline__ ushort_t f2bf(float f) {
    __bf16 b = (__bf16)f;
    union { __bf16 b; ushort_t u; } v; v.b = b; return v.u;
}
__device__ __forceinline__ float bfround(float f) {
    __bf16 b = (__bf16)f; return (float)b;
}

// One v_rcp for four reciprocals: inv[k] = 1/D[k].
// Requires P = D0*D1*D2*D3 finite (caller guarantees via arg bounds/clamps).
__device__ __forceinline__ f32x4 batch_inv4(float D0, float D1, float D2, float D3) {
    float m01 = D0 * D1;
    float m23 = D2 * D3;
    float r   = RCPF(m01 * m23);
    float r01 = r * m23;
    float r23 = r * m01;
    f32x4 o;
    o[0] = r01 * D1;
    o[1] = r01 * D0;
    o[2] = r23 * D3;
    o[3] = r23 * D2;
    return o;
}

struct bfpair { bf16x8 hi, lo; };

// Split 8 consecutive fp32 (scaled by s) into bf16 hi + lo fragments
__device__ __forceinline__ bfpair split8s(const float* __restrict__ p, float s) {
    unsigned short h[8], l[8];
    #pragma unroll
    for (int u = 0; u < 8; ++u) {
        float f = p[u] * s;
        float fh = bfround(f);
        h[u] = f2bf(f);
        l[u] = f2bf(f - fh);
    }
    bfpair r;
    __builtin_memcpy(&r.hi, h, 16);
    __builtin_memcpy(&r.lo, l, 16);
    return r;
}

// launch_bounds (256,3): empirically pins VGPR at 84 (R0/R3/R6). (256,2) let
// VGPR drift to 100 and LOST occupancy (R4); (256,4) forced 64 and spilled
// catastrophically (R2). Do not change.
// Persistent schedule: grid = 1024 = 4 blocks/CU of work, <= resident capacity
// (VGPR-capped ~5 blocks/CU) -> single co-resident round, no ragged 2nd wave.
__global__ __launch_bounds__(256, 3)
void lstm_seq2seq(const float* __restrict__ traj,
                  const float* __restrict__ WihE, const float* __restrict__ WhhE,
                  const float* __restrict__ bihE, const float* __restrict__ bhhE,
                  const float* __restrict__ WihD, const float* __restrict__ WhhD,
                  const float* __restrict__ bihD, const float* __restrict__ bhhD,
                  const float* __restrict__ Wpos, const float* __restrict__ bpos,
                  float* __restrict__ out)
{
    __shared__ __align__(16) ushort_t sHh[2][ROWS * HS];   // h hi [row][unit], double-buffered
    __shared__ __align__(16) ushort_t sHl[2][ROWS * HS];   // h lo
    __shared__ __align__(16) float    sX[ROWS * ENC_T * 2];
    __shared__ __align__(16) float    sP[2][ROWS * 8];     // [row][comp*4 + wave] per-wave sums

    const int tid  = threadIdx.x;
    const int w    = tid >> 6;      // wave -> unit tile (units 16w..16w+15)
    const int lane = tid & 63;
    const int col  = lane & 15;     // n-index: batch row (group 0) for this lane
    const int quad = lane >> 4;     // m-quad: units 16w + quad*4 + r
    const int wg   = blockIdx.x;

    const float gsc[4] = { L2E, L2E, 2.0f * L2E, L2E };  // i,f,g(tanh),o pre-scales

    // projection constants: this lane's 4 units (tile-invariant)
    float wpA[4], wpB[4];
    #pragma unroll
    for (int r = 0; r < 4; ++r) {
        int u = 16 * w + quad * 4 + r;
        wpA[r] = Wpos[u];          // comp 0
        wpB[r] = Wpos[64 + u];     // comp 1
    }
    // distributed reducer constants: 64 tasks = 32 rows x 2 comps, lanes<16 of ALL 4 waves
    const int   rrow  = w * 8 + (lane >> 1);   // 0..31
    const int   rcomp = lane & 1;
    const float bp    = bpos[rcomp];

    for (int tile = 0; tile < TILES; ++tile) {
        const int row0 = (wg * TILES + tile) * ROWS;

        // ---- stage trajectory tile: 1280 contiguous floats (32 rows) ----
        {
            const float* src = traj + (size_t)row0 * (ENC_T * 2);
            #pragma unroll
            for (int i = 0; i < 5; ++i) sX[tid + i * 256] = src[tid + i * 256];
        }
        // ---- zero h buffer 0 ----
        {
            uint_t* hz0 = (uint_t*)&sHh[0][0];
            uint_t* hz1 = (uint_t*)&sHl[0][0];
            for (int j = tid; j < ROWS * HS / 2; j += 256) { hz0[j] = 0; hz1[j] = 0; }
        }

        // ---- encoder per-lane constants: gate j, unit = 16w + quad*4 + r ----
        float wi0[4][4], wi1[4][4], bE[4][4];
        #pragma unroll
        for (int j = 0; j < 4; ++j)
            #pragma unroll
            for (int r = 0; r < 4; ++r) {
                int g = 64 * j + 16 * w + quad * 4 + r;
                wi0[j][r] = WihE[g * 2 + 0] * gsc[j];
                wi1[j][r] = WihE[g * 2 + 1] * gsc[j];
                bE[j][r]  = (bihE[g] + bhhE[g]) * gsc[j];
            }

        // ---- encoder W_hh A-fragments: A[m=col][k=kb*32+quad*8+u] (shared by both row groups) ----
        bfpair bw[4][2];
        #pragma unroll
        for (int j = 0; j < 4; ++j) {
            int g = 64 * j + 16 * w + col;
            #pragma unroll
            for (int kb = 0; kb < 2; ++kb)
                bw[j][kb] = split8s(WhhE + g * 64 + kb * 32 + quad * 8, gsc[j]);
        }

        float c[2][4] = {{0.f,0.f,0.f,0.f},{0.f,0.f,0.f,0.f}};
        int buf = 0;

        __syncthreads();   // staging + h-zero visible (also fences prev tile's sH readers)

        // =========================== ENCODER ===========================
        for (int t = 0; t < ENC_T; ++t) {
            #pragma unroll
            for (int g = 0; g < 2; ++g) {
                const int colg = col + 16 * g;
                f32x4 acc[4];
                {
                    f32x2 xp = *(const f32x2*)&sX[colg * (ENC_T * 2) + 2 * t];
                    #pragma unroll
                    for (int j = 0; j < 4; ++j)
                        #pragma unroll
                        for (int r = 0; r < 4; ++r)
                            acc[j][r] = fmaf(wi1[j][r], xp[1], fmaf(wi0[j][r], xp[0], bE[j][r]));
                }
                // B-frags: h rows, B[n=colg][k]
                bf16x8 b0h = *(const bf16x8*)&sHh[buf][colg * HS +  0 + quad * 8];
                bf16x8 b1h = *(const bf16x8*)&sHh[buf][colg * HS + 32 + quad * 8];
                bf16x8 b0l = *(const bf16x8*)&sHl[buf][colg * HS +  0 + quad * 8];
                bf16x8 b1l = *(const bf16x8*)&sHl[buf][colg * HS + 32 + quad * 8];
                #pragma unroll
                for (int j = 0; j < 4; ++j) {
                    acc[j] = __builtin_amdgcn_mfma_f32_16x16x32_bf16(bw[j][0].hi, b0l, acc[j], 0, 0, 0);
                    acc[j] = __builtin_amdgcn_mfma_f32_16x16x32_bf16(bw[j][1].hi, b1l, acc[j], 0, 0, 0);
                    acc[j] = __builtin_amdgcn_mfma_f32_16x16x32_bf16(bw[j][0].lo, b0h, acc[j], 0, 0, 0);
                    acc[j] = __builtin_amdgcn_mfma_f32_16x16x32_bf16(bw[j][1].lo, b1h, acc[j], 0, 0, 0);
                    acc[j] = __builtin_amdgcn_mfma_f32_16x16x32_bf16(bw[j][0].hi, b0h, acc[j], 0, 0, 0);
                    acc[j] = __builtin_amdgcn_mfma_f32_16x16x32_bf16(bw[j][1].hi, b1h, acc[j], 0, 0, 0);
                }
                // elementwise with batched reciprocals
                float so[4], cnv[4];
                #pragma unroll
                for (int r = 0; r < 4; ++r) {
                    float ei = EXP2F(-acc[0][r]);
                    float ef = EXP2F(-acc[1][r]);
                    float eg = EXP2F(-acc[2][r]);
                    float eo = EXP2F(-acc[3][r]);
                    f32x4 inv = batch_inv4(1.0f + ei, 1.0f + ef, 1.0f + eg, 1.0f + eo);
                    float tg = fmaf(2.0f, inv[2], -1.0f);
                    float cn = fmaf(inv[1], c[g][r], inv[0] * tg);
                    c[g][r] = cn;
                    cnv[r] = cn;
                    so[r] = inv[3];
                }
                float Dc[4];
                #pragma unroll
                for (int r = 0; r < 4; ++r) {
                    float xs = cnv[r] * (-2.0f * L2E);
                    xs = fminf(fmaxf(xs, -30.0f), 30.0f);   // v_med3; keeps P4 finite
                    Dc[r] = 1.0f + EXP2F(xs);
                }
                f32x4 invc = batch_inv4(Dc[0], Dc[1], Dc[2], Dc[3]);
                u16x4 hh, hl;
                #pragma unroll
                for (int r = 0; r < 4; ++r) {
                    float th = fmaf(2.0f, invc[r], -1.0f);
                    float hn = so[r] * th;
                    float fh = bfround(hn);
                    hh[r] = f2bf(hn);
                    hl[r] = f2bf(hn - fh);
                }
                *(u16x4*)&sHh[buf ^ 1][colg * HS + 16 * w + quad * 4] = hh;
                *(u16x4*)&sHl[buf ^ 1][colg * HS + 16 * w + quad * 4] = hl;
            }
            __syncthreads();
            buf ^= 1;
        }

        // ---- decoder combined weights Wc = (W_ih_dec + W_hh_dec)*scale ----
        float bD[4][4];
        #pragma unroll
        for (int j = 0; j < 4; ++j) {
            #pragma unroll
            for (int r = 0; r < 4; ++r) {
                int g = 64 * j + 16 * w + quad * 4 + r;
                bD[j][r] = (bihD[g] + bhhD[g]) * gsc[j];
            }
            int g = 64 * j + 16 * w + col;
            #pragma unroll
            for (int kb = 0; kb < 2; ++kb) {
                int off = g * 64 + kb * 32 + quad * 8;
                float tmp[8];
                #pragma unroll
                for (int u = 0; u < 8; ++u) tmp[u] = WihD[off + u] + WhhD[off + u];
                bw[j][kb] = split8s(tmp, gsc[j]);
            }
        }

        // =========================== DECODER ===========================
        for (int t = 0; t < DEC_T; ++t) {
            #pragma unroll
            for (int g = 0; g < 2; ++g) {
                const int colg = col + 16 * g;
                f32x4 acc[4];
                #pragma unroll
                for (int j = 0; j < 4; ++j)
                    #pragma unroll
                    for (int r = 0; r < 4; ++r)
                        acc[j][r] = bD[j][r];
                bf16x8 b0h = *(const bf16x8*)&sHh[buf][colg * HS +  0 + quad * 8];
                bf16x8 b1h = *(const bf16x8*)&sHh[buf][colg * HS + 32 + quad * 8];
                bf16x8 b0l = *(const bf16x8*)&sHl[buf][colg * HS +  0 + quad * 8];
                bf16x8 b1l = *(const bf16x8*)&sHl[buf][colg * HS + 32 + quad * 8];
                #pragma unroll
                for (int j = 0; j < 4; ++j) {
                    acc[j] = __builtin_amdgcn_mfma_f32_16x16x32_bf16(bw[j][0].hi, b0l, acc[j], 0, 0, 0);
                    acc[j] = __builtin_amdgcn_mfma_f32_16x16x32_bf16(bw[j][1].hi, b1l, acc[j], 0, 0, 0);
                    acc[j] = __builtin_amdgcn_mfma_f32_16x16x32_bf16(bw[j][0].lo, b0h, acc[j], 0, 0, 0);
                    acc[j] = __builtin_amdgcn_mfma_f32_16x16x32_bf16(bw[j][1].lo, b1h, acc[j], 0, 0, 0);
                    acc[j] = __builtin_amdgcn_mfma_f32_16x16x32_bf16(bw[j][0].hi, b0h, acc[j], 0, 0, 0);
                    acc[j] = __builtin_amdgcn_mfma_f32_16x16x32_bf16(bw[j][1].hi, b1h, acc[j], 0, 0, 0);
                }
                // elementwise with batched reciprocals
                float so[4], cnv[4];
                #pragma unroll
                for (int r = 0; r < 4; ++r) {
                    float ei = EXP2F(-acc[0][r]);
                    float ef = EXP2F(-acc[1][r]);
                    float eg = EXP2F(-acc[2][r]);
                    float eo = EXP2F(-acc[3][r]);
                    f32x4 inv = batch_inv4(1.0f + ei, 1.0f + ef, 1.0f + eg, 1.0f + eo);
                    float tg = fmaf(2.0f, inv[2], -1.0f);
                    float cn = fmaf(inv[1], c[g][r], inv[0] * tg);
                    c[g][r] = cn;
                    cnv[r] = cn;
                    so[r] = inv[3];
                }
                float Dc[4];
                #pragma unroll
                for (int r = 0; r < 4; ++r) {
                    float xs = cnv[r] * (-2.0f * L2E);
                    xs = fminf(fmaxf(xs, -30.0f), 30.0f);
                    Dc[r] = 1.0f + EXP2F(xs);
                }
                f32x4 invc = batch_inv4(Dc[0], Dc[1], Dc[2], Dc[3]);
                u16x4 hh, hl;
                float p0 = 0.f, p1 = 0.f;
                #pragma unroll
                for (int r = 0; r < 4; ++r) {
                    float th = fmaf(2.0f, invc[r], -1.0f);
                    float hn = so[r] * th;
                    p0 = fmaf(hn, wpA[r], p0);
                    p1 = fmaf(hn, wpB[r], p1);
                    float fh = bfround(hn);
                    hh[r] = f2bf(hn);
                    hl[r] = f2bf(hn - fh);
                }
                *(u16x4*)&sHh[buf ^ 1][colg * HS + 16 * w + quad * 4] = hh;
                *(u16x4*)&sHl[buf ^ 1][colg * HS + 16 * w + quad * 4] = hl;
                // in-wave quad reduction of projection partials (verified R4/R6):
                // lanes with same col across quads sum -> one value per (row, comp, wave)
                p0 += __shfl_xor(p0, 16, 64);
                p0 += __shfl_xor(p0, 32, 64);
                p1 += __shfl_xor(p1, 16, 64);
                p1 += __shfl_xor(p1, 32, 64);
                if (quad == 0) {
                    sP[buf ^ 1][colg * 8 + 0 + w] = p0;
                    sP[buf ^ 1][colg * 8 + 4 + w] = p1;
                }
            }
            __syncthreads();
            buf ^= 1;
            // distributed output reduction: 64 tasks over lanes<16 of all 4 waves.
            // sP double-buffered: step t+1 writes the OTHER buffer, so readers of
            // step t are race-free past this barrier (same scheme as sH). Across
            // tiles: next sP write is 20+ barriers away (encoder), race-free.
            if (lane < 16) {
                f32x4 v = *(const f32x4*)&sP[buf][rrow * 8 + rcomp * 4];
                float p = (v[0] + v[1]) + (v[2] + v[3]) + bp;
                out[(size_t)(row0 + rrow) * (DEC_T * 2) + t * 2 + rcomp] = p;
            }
        }
    }
}

extern "C" void kernel_launch(void* const* d_in, const int* in_sizes, int n_in,
                              void* d_out, int out_size, void* d_ws, size_t ws_size,
                              hipStream_t stream) {
    const float* traj = (const float*)d_in[0];
    const float* WihE = (const float*)d_in[1];
    const float* WhhE = (const float*)d_in[2];
    const float* bihE = (const float*)d_in[3];
    const float* bhhE = (const float*)d_in[4];
    const float* WihD = (const float*)d_in[5];
    const float* WhhD = (const float*)d_in[6];
    const float* bihD = (const float*)d_in[7];
    const float* bhhD = (const float*)d_in[8];
    const float* Wpos = (const float*)d_in[9];
    const float* bpos = (const float*)d_in[10];
    float* out = (float*)d_out;

    const int B = in_sizes[0] / (ENC_T * 2);   // 65536
    const int grid = B / (ROWS * TILES);       // 1024 blocks = 4 per CU, single round

    lstm_seq2seq<<<grid, 256, 0, stream>>>(traj, WihE, WhhE, bihE, bhhE,
                                           WihD, WhhD, bihD, bhhD, Wpos, bpos, out);
}

// Round 8
// 377.266 us; speedup vs baseline: 4.4587x; 4.4587x over previous
//
#include <hip/hip_runtime.h>

#define HID   64
#define ENC_T 20
#define DEC_T 30
#define ROWS  32   // batch rows per workgroup: two 16-row MFMA n-tiles per wave
#define HS    72   // sH row stride in f16 elems: 144B = 16B-aligned

typedef _Float16 f16;
typedef _Float16 f16x8 __attribute__((ext_vector_type(8)));
typedef _Float16 f16x4 __attribute__((ext_vector_type(4)));
typedef float  f32x4  __attribute__((ext_vector_type(4)));
typedef float  f32x2  __attribute__((ext_vector_type(2)));
typedef unsigned int   uint_t;

#if __has_builtin(__builtin_amdgcn_exp2f)
#define EXP2F(x) __builtin_amdgcn_exp2f(x)
#else
#define EXP2F(x) exp2f(x)
#endif
#if __has_builtin(__builtin_amdgcn_rcpf)
#define RCPF(x) __builtin_amdgcn_rcpf(x)
#else
#define RCPF(x) (1.0f / (x))
#endif

#define L2E 1.4426950408889634f

// One v_rcp for four reciprocals: inv[k] = 1/D[k].
// Requires P = D0*D1*D2*D3 finite (caller guarantees via arg bounds/clamps).
__device__ __forceinline__ f32x4 batch_inv4(float D0, float D1, float D2, float D3) {
    float m01 = D0 * D1;
    float m23 = D2 * D3;
    float r   = RCPF(m01 * m23);
    float r01 = r * m23;
    float r23 = r * m01;
    f32x4 o;
    o[0] = r01 * D1;
    o[1] = r01 * D0;
    o[2] = r23 * D3;
    o[3] = r23 * D2;
    return o;
}

// 8 consecutive fp32 (scaled) -> f16 frag
__device__ __forceinline__ f16x8 load8h(const float* __restrict__ p, float s) {
    f16x8 r;
    #pragma unroll
    for (int u = 0; u < 8; ++u) r[u] = (f16)(p[u] * s);
    return r;
}

// launch_bounds cap model (measured R2/R4/R6/R7): VGPR cap ~= 256/N.
// N=2 -> 128 cap; est. peak need ~108 -> no spill. N=3's 84 cap spilled
// the R7 tile loop; N=4's 64 cap spilled catastrophically (R2).
__global__ __launch_bounds__(256, 2)
void lstm_seq2seq(const float* __restrict__ traj,
                  const float* __restrict__ WihE, const float* __restrict__ WhhE,
                  const float* __restrict__ bihE, const float* __restrict__ bhhE,
                  const float* __restrict__ WihD, const float* __restrict__ WhhD,
                  const float* __restrict__ bihD, const float* __restrict__ bhhD,
                  const float* __restrict__ Wpos, const float* __restrict__ bpos,
                  float* __restrict__ out)
{
    __shared__ __align__(16) f16   sH[2][ROWS * HS];    // h (single f16), double-buffered
    __shared__ __align__(16) float sX[ROWS * ENC_T * 2];
    __shared__ __align__(16) float sP[2][ROWS * 8];     // [row][comp*4 + wave] per-wave sums

    const int tid  = threadIdx.x;
    const int w    = tid >> 6;      // wave -> unit tile (units 16w..16w+15)
    const int lane = tid & 63;
    const int col  = lane & 15;     // n-index: batch row (group 0) for this lane
    const int quad = lane >> 4;     // m-quad: C rows = units 16w + quad*4 + r
    const int wg   = blockIdx.x;

    const float gsc[4] = { L2E, L2E, 2.0f * L2E, L2E };  // i,f,g(tanh),o pre-scales

    // ---- stage trajectory tile: 1280 contiguous floats (32 rows) ----
    {
        const float* src = traj + (size_t)wg * (ROWS * ENC_T * 2);
        #pragma unroll
        for (int i = 0; i < 5; ++i) sX[tid + i * 256] = src[tid + i * 256];
    }
    // ---- zero h buffer 0 ----
    {
        uint_t* hz = (uint_t*)&sH[0][0];
        for (int j = tid; j < ROWS * HS / 2; j += 256) hz[j] = 0;
    }

    // ---- encoder A-fragments (f16). bw[j][0..1]: Whh k-blocks (A[m=col][k]).
    //      bw[j][2]: x+bias fold block: k-slots {W0hi,W1hi,W0lo,W1lo,b_hi,b_lo}
    //      (x kept hi/lo-exact on the B side; only Whh*h is f16-single). ----
    // NOTE: A-side rows are m=col (NOT quad*4+r) — bias must be col-indexed here.
    f16x8 bw[4][3];
    #pragma unroll
    for (int j = 0; j < 4; ++j) {
        int g = 64 * j + 16 * w + col;
        #pragma unroll
        for (int kb = 0; kb < 2; ++kb)
            bw[j][kb] = load8h(WhhE + g * 64 + kb * 32 + quad * 8, gsc[j]);
        float w0 = WihE[g * 2 + 0] * gsc[j];
        float w1 = WihE[g * 2 + 1] * gsc[j];
        float bs = (bihE[g] + bhhE[g]) * gsc[j];
        f16 w0h = (f16)w0, w1h = (f16)w1, bh = (f16)bs;
        f16 w0l = (f16)(w0 - (float)w0h);
        f16 w1l = (f16)(w1 - (float)w1h);
        f16 bl  = (f16)(bs - (float)bh);
        f16x8 a2 = {};
        if (quad == 0) {
            a2[0] = w0h; a2[1] = w1h; a2[2] = w0l; a2[3] = w1l; a2[4] = bh; a2[5] = bl;
        }
        bw[j][2] = a2;
    }

    float c[2][4] = {{0.f,0.f,0.f,0.f},{0.f,0.f,0.f,0.f}};
    int buf = 0;

    __syncthreads();

    // =========================== ENCODER ===========================
    for (int t = 0; t < ENC_T; ++t) {
        #pragma unroll
        for (int g = 0; g < 2; ++g) {
            const int colg = col + 16 * g;
            // B2: x+bias block. B[n=colg][k]: quad0 holds {x0h,x1h,x0l,x1l,1,1}
            f32x2 xp = *(const f32x2*)&sX[colg * (ENC_T * 2) + 2 * t];
            f16 xh0 = (f16)xp[0], xh1 = (f16)xp[1];
            f16 xl0 = (f16)(xp[0] - (float)xh0);
            f16 xl1 = (f16)(xp[1] - (float)xh1);
            f16x8 b2 = {};
            if (quad == 0) {
                b2[0] = xh0; b2[1] = xh1; b2[2] = xl0; b2[3] = xl1;
                b2[4] = (f16)1; b2[5] = (f16)1;
            }
            f16x8 b0 = *(const f16x8*)&sH[buf][colg * HS +  0 + quad * 8];
            f16x8 b1 = *(const f16x8*)&sH[buf][colg * HS + 32 + quad * 8];
            f32x4 acc[4] = {{0,0,0,0},{0,0,0,0},{0,0,0,0},{0,0,0,0}};
            #pragma unroll
            for (int j = 0; j < 4; ++j) {
                acc[j] = __builtin_amdgcn_mfma_f32_16x16x32_f16(bw[j][2], b2, acc[j], 0, 0, 0);
                acc[j] = __builtin_amdgcn_mfma_f32_16x16x32_f16(bw[j][0], b0, acc[j], 0, 0, 0);
                acc[j] = __builtin_amdgcn_mfma_f32_16x16x32_f16(bw[j][1], b1, acc[j], 0, 0, 0);
            }
            // elementwise with batched reciprocals
            float so[4], cnv[4];
            #pragma unroll
            for (int r = 0; r < 4; ++r) {
                float ei = EXP2F(-acc[0][r]);
                float ef = EXP2F(-acc[1][r]);
                float eg = EXP2F(-acc[2][r]);
                float eo = EXP2F(-acc[3][r]);
                f32x4 inv = batch_inv4(1.0f + ei, 1.0f + ef, 1.0f + eg, 1.0f + eo);
                float tg = fmaf(2.0f, inv[2], -1.0f);
                float cn = fmaf(inv[1], c[g][r], inv[0] * tg);
                c[g][r] = cn;
                cnv[r] = cn;
                so[r] = inv[3];
            }
            float Dc[4];
            #pragma unroll
            for (int r = 0; r < 4; ++r) {
                float xs = cnv[r] * (-2.0f * L2E);
                xs = fminf(fmaxf(xs, -30.0f), 30.0f);   // v_med3; keeps P4 finite
                Dc[r] = 1.0f + EXP2F(xs);
            }
            f32x4 invc = batch_inv4(Dc[0], Dc[1], Dc[2], Dc[3]);
            f16x4 hh;
            #pragma unroll
            for (int r = 0; r < 4; ++r) {
                float th = fmaf(2.0f, invc[r], -1.0f);
                float hn = so[r] * th;
                hh[r] = (f16)hn;
            }
            *(f16x4*)&sH[buf ^ 1][colg * HS + 16 * w + quad * 4] = hh;
        }
        __syncthreads();
        buf ^= 1;
    }

    // ---- decoder A-fragments: Wc = (W_ih_dec + W_hh_dec)*gsc, f16 single;
    //      bias folded in k-block 2 (slots {b_hi, b_lo}) ----
    #pragma unroll
    for (int j = 0; j < 4; ++j) {
        int g = 64 * j + 16 * w + col;
        #pragma unroll
        for (int kb = 0; kb < 2; ++kb) {
            int off = g * 64 + kb * 32 + quad * 8;
            float tmp[8];
            #pragma unroll
            for (int u = 0; u < 8; ++u) tmp[u] = WihD[off + u] + WhhD[off + u];
            bw[j][kb] = load8h(tmp, gsc[j]);
        }
        float bs = (bihD[g] + bhhD[g]) * gsc[j];
        f16 bh = (f16)bs;
        f16 bl = (f16)(bs - (float)bh);
        f16x8 a2 = {};
        if (quad == 0) { a2[0] = bh; a2[1] = bl; }
        bw[j][2] = a2;
    }
    // constant B2 for decoder: quad0 {1,1,0,...}
    f16x8 b2d = {};
    if (quad == 0) { b2d[0] = (f16)1; b2d[1] = (f16)1; }

    // projection constants: this lane's 4 units (shared by both row groups)
    float wpA[4], wpB[4];
    #pragma unroll
    for (int r = 0; r < 4; ++r) {
        int u = 16 * w + quad * 4 + r;
        wpA[r] = Wpos[u];          // comp 0
        wpB[r] = Wpos[64 + u];     // comp 1
    }
    // distributed reducer constants: 64 tasks = 32 rows x 2 comps, lanes<16 of ALL 4 waves
    const int   rrow  = w * 8 + (lane >> 1);   // 0..31
    const int   rcomp = lane & 1;
    const float bp    = bpos[rcomp];

    // =========================== DECODER ===========================
    for (int t = 0; t < DEC_T; ++t) {
        #pragma unroll
        for (int g = 0; g < 2; ++g) {
            const int colg = col + 16 * g;
            f16x8 b0 = *(const f16x8*)&sH[buf][colg * HS +  0 + quad * 8];
            f16x8 b1 = *(const f16x8*)&sH[buf][colg * HS + 32 + quad * 8];
            f32x4 acc[4] = {{0,0,0,0},{0,0,0,0},{0,0,0,0},{0,0,0,0}};
            #pragma unroll
            for (int j = 0; j < 4; ++j) {
                acc[j] = __builtin_amdgcn_mfma_f32_16x16x32_f16(bw[j][2], b2d, acc[j], 0, 0, 0);
                acc[j] = __builtin_amdgcn_mfma_f32_16x16x32_f16(bw[j][0], b0, acc[j], 0, 0, 0);
                acc[j] = __builtin_amdgcn_mfma_f32_16x16x32_f16(bw[j][1], b1, acc[j], 0, 0, 0);
            }
            // elementwise with batched reciprocals
            float so[4], cnv[4];
            #pragma unroll
            for (int r = 0; r < 4; ++r) {
                float ei = EXP2F(-acc[0][r]);
                float ef = EXP2F(-acc[1][r]);
                float eg = EXP2F(-acc[2][r]);
                float eo = EXP2F(-acc[3][r]);
                f32x4 inv = batch_inv4(1.0f + ei, 1.0f + ef, 1.0f + eg, 1.0f + eo);
                float tg = fmaf(2.0f, inv[2], -1.0f);
                float cn = fmaf(inv[1], c[g][r], inv[0] * tg);
                c[g][r] = cn;
                cnv[r] = cn;
                so[r] = inv[3];
            }
            float Dc[4];
            #pragma unroll
            for (int r = 0; r < 4; ++r) {
                float xs = cnv[r] * (-2.0f * L2E);
                xs = fminf(fmaxf(xs, -30.0f), 30.0f);
                Dc[r] = 1.0f + EXP2F(xs);
            }
            f32x4 invc = batch_inv4(Dc[0], Dc[1], Dc[2], Dc[3]);
            f16x4 hh;
            float p0 = 0.f, p1 = 0.f;
            #pragma unroll
            for (int r = 0; r < 4; ++r) {
                float th = fmaf(2.0f, invc[r], -1.0f);
                float hn = so[r] * th;
                p0 = fmaf(hn, wpA[r], p0);
                p1 = fmaf(hn, wpB[r], p1);
                hh[r] = (f16)hn;
            }
            *(f16x4*)&sH[buf ^ 1][colg * HS + 16 * w + quad * 4] = hh;
            // in-wave quad reduction of projection partials (verified R4/R6):
            p0 += __shfl_xor(p0, 16, 64);
            p0 += __shfl_xor(p0, 32, 64);
            p1 += __shfl_xor(p1, 16, 64);
            p1 += __shfl_xor(p1, 32, 64);
            if (quad == 0) {
                sP[buf ^ 1][colg * 8 + 0 + w] = p0;
                sP[buf ^ 1][colg * 8 + 4 + w] = p1;
            }
        }
        __syncthreads();
        buf ^= 1;
        // distributed output reduction: 64 tasks over lanes<16 of all 4 waves.
        // sP double-buffered: step t+1 writes the OTHER buffer, so readers of
        // step t are race-free past this barrier (same scheme as sH).
        if (lane < 16) {
            f32x4 v = *(const f32x4*)&sP[buf][rrow * 8 + rcomp * 4];
            float p = (v[0] + v[1]) + (v[2] + v[3]) + bp;
            out[(size_t)(wg * ROWS + rrow) * (DEC_T * 2) + t * 2 + rcomp] = p;
        }
    }
}

extern "C" void kernel_launch(void* const* d_in, const int* in_sizes, int n_in,
                              void* d_out, int out_size, void* d_ws, size_t ws_size,
                              hipStream_t stream) {
    const float* traj = (const float*)d_in[0];
    const float* WihE = (const float*)d_in[1];
    const float* WhhE = (const float*)d_in[2];
    const float* bihE = (const float*)d_in[3];
    const float* bhhE = (const float*)d_in[4];
    const float* WihD = (const float*)d_in[5];
    const float* WhhD = (const float*)d_in[6];
    const float* bihD = (const float*)d_in[7];
    const float* bhhD = (const float*)d_in[8];
    const float* Wpos = (const float*)d_in[9];
    const float* bpos = (const float*)d_in[10];
    float* out = (float*)d_out;

    const int B = in_sizes[0] / (ENC_T * 2);   // 65536
    const int grid = B / ROWS;                 // 2048 workgroups, 32 rows each

    lstm_seq2seq<<<grid, 256, 0, stream>>>(traj, WihE, WhhE, bihE, bhhE,
                                           WihD, WhhD, bihD, bhhD, Wpos, bpos, out);
}

// Round 9
// 316.349 us; speedup vs baseline: 5.3173x; 1.1926x over previous
//
#include <hip/hip_runtime.h>

#define HID   64
#define ENC_T 20
#define DEC_T 30
#define ROWS  32   // batch rows per workgroup: two 16-row MFMA n-tiles per wave
#define HS    72   // sH row stride in f16 elems: 144B = 16B-aligned

typedef _Float16 f16;
typedef _Float16 f16x8 __attribute__((ext_vector_type(8)));
typedef _Float16 f16x4 __attribute__((ext_vector_type(4)));
typedef float  f32x4  __attribute__((ext_vector_type(4)));
typedef float  f32x2  __attribute__((ext_vector_type(2)));
typedef unsigned int   uint_t;

#if __has_builtin(__builtin_amdgcn_exp2f)
#define EXP2F(x) __builtin_amdgcn_exp2f(x)
#else
#define EXP2F(x) exp2f(x)
#endif
#if __has_builtin(__builtin_amdgcn_rcpf)
#define RCPF(x) __builtin_amdgcn_rcpf(x)
#else
#define RCPF(x) (1.0f / (x))
#endif

#define L2E 1.4426950408889634f

// One v_rcp for four reciprocals (KEEP: R1->R3 calibration shows trans ops are
// ~8-9 cyc/wave quarter-rate, so trading 3 rcp for 8 muls wins ~35 cyc/group-step).
__device__ __forceinline__ f32x4 batch_inv4(float D0, float D1, float D2, float D3) {
    float m01 = D0 * D1;
    float m23 = D2 * D3;
    float r   = RCPF(m01 * m23);
    float r01 = r * m23;
    float r23 = r * m01;
    f32x4 o;
    o[0] = r01 * D1;
    o[1] = r01 * D0;
    o[2] = r23 * D3;
    o[3] = r23 * D2;
    return o;
}

// 8 consecutive fp32 (scaled) -> f16 frag
__device__ __forceinline__ f16x8 load8h(const float* __restrict__ p, float s) {
    f16x8 r;
    #pragma unroll
    for (int u = 0; u < 8; ++u) r[u] = (f16)(p[u] * s);
    return r;
}

// launch_bounds cap model (measured R2/R4/R6/R7): VGPR cap ~= 256/N.
// N=2 -> 128 cap; est. need ~105 -> margin. N=3 (84) / N=4 (64) spill this body.
__global__ __launch_bounds__(256, 2)
void lstm_seq2seq(const float* __restrict__ traj,
                  const float* __restrict__ WihE, const float* __restrict__ WhhE,
                  const float* __restrict__ bihE, const float* __restrict__ bhhE,
                  const float* __restrict__ WihD, const float* __restrict__ WhhD,
                  const float* __restrict__ bihD, const float* __restrict__ bhhD,
                  const float* __restrict__ Wpos, const float* __restrict__ bpos,
                  float* __restrict__ out)
{
    __shared__ __align__(16) f16   sH[2][ROWS * HS];    // h (single f16), double-buffered
    __shared__ __align__(16) f16x4 sXh[ROWS * ENC_T + ENC_T]; // {xh0,xh1,xl0,xl1} + 20 zero slots
    __shared__ __align__(16) float sP[2][ROWS * 8];     // [row][comp*4 + wave] per-wave sums

    const int tid  = threadIdx.x;
    const int w    = tid >> 6;      // wave -> unit tile (units 16w..16w+15)
    const int lane = tid & 63;
    const int col  = lane & 15;     // n-index: batch row (group 0) for this lane
    const int quad = lane >> 4;     // m-quad: C rows = units 16w + quad*4 + r
    const int wg   = blockIdx.x;

    const float gsc[4] = { L2E, L2E, 2.0f * L2E, L2E };  // i,f,g(tanh),o pre-scales

    // ---- stage trajectory as preconverted f16 hi/lo blocks (once, not per step/wave) ----
    {
        const float* src = traj + (size_t)wg * (ROWS * ENC_T * 2);
        for (int p = tid; p < ROWS * ENC_T; p += 256) {
            f32x2 xp = *(const f32x2*)(src + 2 * p);
            f16 xh0 = (f16)xp[0], xh1 = (f16)xp[1];
            f16x4 v;
            v[0] = xh0; v[1] = xh1;
            v[2] = (f16)(xp[0] - (float)xh0);
            v[3] = (f16)(xp[1] - (float)xh1);
            sXh[p] = v;
        }
        if (tid < ENC_T) {              // zero slots: quad!=0 lanes read here
            f16x4 zz = {};
            sXh[ROWS * ENC_T + tid] = zz;
        }
    }
    // ---- zero h buffer 0 ----
    {
        uint_t* hz = (uint_t*)&sH[0][0];
        for (int j = tid; j < ROWS * HS / 2; j += 256) hz[j] = 0;
    }

    // ---- encoder A-fragments (f16). bw[j][0..1]: Whh k-blocks (A[m=col][k]).
    //      bw[j][2]: x+bias fold block: k-slots {W0hi,W1hi,W0lo,W1lo,b_hi,b_lo}
    //      (A-side rows are m=col; bias col-indexed here). ----
    f16x8 bw[4][3];
    #pragma unroll
    for (int j = 0; j < 4; ++j) {
        int g = 64 * j + 16 * w + col;
        #pragma unroll
        for (int kb = 0; kb < 2; ++kb)
            bw[j][kb] = load8h(WhhE + g * 64 + kb * 32 + quad * 8, gsc[j]);
        float w0 = WihE[g * 2 + 0] * gsc[j];
        float w1 = WihE[g * 2 + 1] * gsc[j];
        float bs = (bihE[g] + bhhE[g]) * gsc[j];
        f16 w0h = (f16)w0, w1h = (f16)w1, bh = (f16)bs;
        f16 w0l = (f16)(w0 - (float)w0h);
        f16 w1l = (f16)(w1 - (float)w1h);
        f16 bl  = (f16)(bs - (float)bh);
        f16x8 a2 = {};
        if (quad == 0) {
            a2[0] = w0h; a2[1] = w1h; a2[2] = w0l; a2[3] = w1l; a2[4] = bh; a2[5] = bl;
        }
        bw[j][2] = a2;
    }

    // hoisted per-lane constants for the encoder B2 block
    const uint_t onesd = (quad == 0) ? 0x3C003C00u : 0u;     // f16 {1,1} or {0,0}
    const int xbase0 = (quad == 0) ? (col      * ENC_T) : (ROWS * ENC_T);  // g=0
    const int xbase1 = (quad == 0) ? ((col+16) * ENC_T) : (ROWS * ENC_T);  // g=1
    const f32x4 z4 = { 0.f, 0.f, 0.f, 0.f };                 // shared zero C (4 regs)

    float c[2][4] = {{0.f,0.f,0.f,0.f},{0.f,0.f,0.f,0.f}};
    int buf = 0;

    __syncthreads();

    // =========================== ENCODER ===========================
    for (int t = 0; t < ENC_T; ++t) {
        #pragma unroll
        for (int g = 0; g < 2; ++g) {
            const int colg = col + 16 * g;
            // B2: one 8B LDS read (zero slot for quad!=0) + hoisted ones dword
            union { f16x4 v; uint_t d[2]; } xfu;
            xfu.v = sXh[(g ? xbase1 : xbase0) + t];
            union { f16x8 v; uint_t d[4]; } b2u;
            b2u.d[0] = xfu.d[0];
            b2u.d[1] = xfu.d[1];
            b2u.d[2] = onesd;
            b2u.d[3] = 0;
            f16x8 b0 = *(const f16x8*)&sH[buf][colg * HS +  0 + quad * 8];
            f16x8 b1 = *(const f16x8*)&sH[buf][colg * HS + 32 + quad * 8];
            f32x4 acc[4];
            #pragma unroll
            for (int j = 0; j < 4; ++j) {
                acc[j] = __builtin_amdgcn_mfma_f32_16x16x32_f16(bw[j][2], b2u.v, z4, 0, 0, 0);
                acc[j] = __builtin_amdgcn_mfma_f32_16x16x32_f16(bw[j][0], b0, acc[j], 0, 0, 0);
                acc[j] = __builtin_amdgcn_mfma_f32_16x16x32_f16(bw[j][1], b1, acc[j], 0, 0, 0);
            }
            // elementwise with batched reciprocals
            float so[4], cnv[4];
            #pragma unroll
            for (int r = 0; r < 4; ++r) {
                float ei = EXP2F(-acc[0][r]);
                float ef = EXP2F(-acc[1][r]);
                float eg = EXP2F(-acc[2][r]);
                float eo = EXP2F(-acc[3][r]);
                f32x4 inv = batch_inv4(1.0f + ei, 1.0f + ef, 1.0f + eg, 1.0f + eo);
                float tg = fmaf(2.0f, inv[2], -1.0f);
                float cn = fmaf(inv[1], c[g][r], inv[0] * tg);
                c[g][r] = cn;
                cnv[r] = cn;
                so[r] = inv[3];
            }
            float Dc[4];
            #pragma unroll
            for (int r = 0; r < 4; ++r) {
                float xs = cnv[r] * (-2.0f * L2E);
                xs = fminf(fmaxf(xs, -30.0f), 30.0f);   // v_med3; keeps P4 finite
                Dc[r] = 1.0f + EXP2F(xs);
            }
            f32x4 invc = batch_inv4(Dc[0], Dc[1], Dc[2], Dc[3]);
            f16x4 hh;
            #pragma unroll
            for (int r = 0; r < 4; ++r) {
                float th = fmaf(2.0f, invc[r], -1.0f);
                float hn = so[r] * th;
                hh[r] = (f16)hn;
            }
            *(f16x4*)&sH[buf ^ 1][colg * HS + 16 * w + quad * 4] = hh;
        }
        __syncthreads();
        buf ^= 1;
    }

    // ---- decoder A-fragments: Wc = (W_ih_dec + W_hh_dec)*gsc, f16 single.
    //      Bias as MFMA C-input (quad-indexed rows) — no fold MFMA needed. ----
    f32x4 bD4[4];
    #pragma unroll
    for (int j = 0; j < 4; ++j) {
        int g = 64 * j + 16 * w + col;
        #pragma unroll
        for (int kb = 0; kb < 2; ++kb) {
            int off = g * 64 + kb * 32 + quad * 8;
            float tmp[8];
            #pragma unroll
            for (int u = 0; u < 8; ++u) tmp[u] = WihD[off + u] + WhhD[off + u];
            bw[j][kb] = load8h(tmp, gsc[j]);
        }
        #pragma unroll
        for (int r = 0; r < 4; ++r) {
            int gr = 64 * j + 16 * w + quad * 4 + r;   // C-row indexing
            bD4[j][r] = (bihD[gr] + bhhD[gr]) * gsc[j];
        }
    }

    // projection constants: this lane's 4 units (shared by both row groups)
    float wpA[4], wpB[4];
    #pragma unroll
    for (int r = 0; r < 4; ++r) {
        int u = 16 * w + quad * 4 + r;
        wpA[r] = Wpos[u];          // comp 0
        wpB[r] = Wpos[64 + u];     // comp 1
    }
    // distributed reducer constants: 64 tasks = 32 rows x 2 comps, lanes<16 of ALL 4 waves
    const int   rrow  = w * 8 + (lane >> 1);   // 0..31
    const int   rcomp = lane & 1;
    const float bp    = bpos[rcomp];

    // =========================== DECODER ===========================
    for (int t = 0; t < DEC_T; ++t) {
        #pragma unroll
        for (int g = 0; g < 2; ++g) {
            const int colg = col + 16 * g;
            f16x8 b0 = *(const f16x8*)&sH[buf][colg * HS +  0 + quad * 8];
            f16x8 b1 = *(const f16x8*)&sH[buf][colg * HS + 32 + quad * 8];
            f32x4 acc[4];
            #pragma unroll
            for (int j = 0; j < 4; ++j) {
                acc[j] = __builtin_amdgcn_mfma_f32_16x16x32_f16(bw[j][0], b0, bD4[j], 0, 0, 0);
                acc[j] = __builtin_amdgcn_mfma_f32_16x16x32_f16(bw[j][1], b1, acc[j], 0, 0, 0);
            }
            // elementwise with batched reciprocals
            float so[4], cnv[4];
            #pragma unroll
            for (int r = 0; r < 4; ++r) {
                float ei = EXP2F(-acc[0][r]);
                float ef = EXP2F(-acc[1][r]);
                float eg = EXP2F(-acc[2][r]);
                float eo = EXP2F(-acc[3][r]);
                f32x4 inv = batch_inv4(1.0f + ei, 1.0f + ef, 1.0f + eg, 1.0f + eo);
                float tg = fmaf(2.0f, inv[2], -1.0f);
                float cn = fmaf(inv[1], c[g][r], inv[0] * tg);
                c[g][r] = cn;
                cnv[r] = cn;
                so[r] = inv[3];
            }
            float Dc[4];
            #pragma unroll
            for (int r = 0; r < 4; ++r) {
                float xs = cnv[r] * (-2.0f * L2E);
                xs = fminf(fmaxf(xs, -30.0f), 30.0f);
                Dc[r] = 1.0f + EXP2F(xs);
            }
            f32x4 invc = batch_inv4(Dc[0], Dc[1], Dc[2], Dc[3]);
            f16x4 hh;
            float p0 = 0.f, p1 = 0.f;
            #pragma unroll
            for (int r = 0; r < 4; ++r) {
                float th = fmaf(2.0f, invc[r], -1.0f);
                float hn = so[r] * th;
                p0 = fmaf(hn, wpA[r], p0);
                p1 = fmaf(hn, wpB[r], p1);
                hh[r] = (f16)hn;
            }
            *(f16x4*)&sH[buf ^ 1][colg * HS + 16 * w + quad * 4] = hh;
            // in-wave quad reduction of projection partials (verified R4/R6):
            p0 += __shfl_xor(p0, 16, 64);
            p0 += __shfl_xor(p0, 32, 64);
            p1 += __shfl_xor(p1, 16, 64);
            p1 += __shfl_xor(p1, 32, 64);
            if (quad == 0) {
                sP[buf ^ 1][colg * 8 + 0 + w] = p0;
                sP[buf ^ 1][colg * 8 + 4 + w] = p1;
            }
        }
        __syncthreads();
        buf ^= 1;
        // distributed output reduction: 64 tasks over lanes<16 of all 4 waves.
        // sP double-buffered: step t+1 writes the OTHER buffer -> race-free.
        if (lane < 16) {
            f32x4 v = *(const f32x4*)&sP[buf][rrow * 8 + rcomp * 4];
            float p = (v[0] + v[1]) + (v[2] + v[3]) + bp;
            out[(size_t)(wg * ROWS + rrow) * (DEC_T * 2) + t * 2 + rcomp] = p;
        }
    }
}

extern "C" void kernel_launch(void* const* d_in, const int* in_sizes, int n_in,
                              void* d_out, int out_size, void* d_ws, size_t ws_size,
                              hipStream_t stream) {
    const float* traj = (const float*)d_in[0];
    const float* WihE = (const float*)d_in[1];
    const float* WhhE = (const float*)d_in[2];
    const float* bihE = (const float*)d_in[3];
    const float* bhhE = (const float*)d_in[4];
    const float* WihD = (const float*)d_in[5];
    const float* WhhD = (const float*)d_in[6];
    const float* bihD = (const float*)d_in[7];
    const float* bhhD = (const float*)d_in[8];
    const float* Wpos = (const float*)d_in[9];
    const float* bpos = (const float*)d_in[10];
    float* out = (float*)d_out;

    const int B = in_sizes[0] / (ENC_T * 2);   // 65536
    const int grid = B / ROWS;                 // 2048 workgroups, 32 rows each

    lstm_seq2seq<<<grid, 256, 0, stream>>>(traj, WihE, WhhE, bihE, bhhE,
                                           WihD, WhhD, bihD, bhhD, Wpos, bpos, out);
}